// Round 12
// baseline (841.358 us; speedup 1.0000x reference)
//
#include <hip/hip_runtime.h>
#include <hip/hip_cooperative_groups.h>

namespace cg = cooperative_groups;

#define NN 50000
#define NE 600000
#define DIM 128
#define NSCAN 196  // ceil(50000/256)
#define TILES 3125 // 50000/16
#define ROWW 136   // LDS row pitch in u16 (128 + 8 pad)
#define NEPAD (NE + 8 * NN + 64)  // rows padded to multiple of 8, min 8

typedef unsigned short u16;
typedef unsigned int u32;
typedef __attribute__((ext_vector_type(8))) short bf16x8;
typedef __attribute__((ext_vector_type(4))) float f32x4;

__device__ __forceinline__ u16 f2bf(float f) {
    u32 u = __builtin_bit_cast(u32, f);
    u32 r = (u + 0x7FFFu + ((u >> 16) & 1u)) >> 16;
    return (u16)r;
}
__device__ __forceinline__ float bflo(u32 w) { return __builtin_bit_cast(float, w << 16); }
__device__ __forceinline__ float bfhi(u32 w) { return __builtin_bit_cast(float, w & 0xffff0000u); }
__device__ __forceinline__ int pad8(int d) {
    int p = (d + 7) & ~7;
    return p < 8 ? 8 : p;
}

struct Params {
    const int* ei;
    int* deg;     // cursor = deg + NN (both zeroed in phase 0)
    int* recs;
    float* dinv;
    int* rp8;
    int* bsum;
    u16* Wt;
    u16* hwA;
    u16* hwB;
    const float* x;
    const float* W0;
    const float* W1;
    const float* W2;
    const float* b0;
    const float* b1;
    const float* b2;
    float* out;
};

// ---- phase bodies (R8-verbatim, blockIdx -> bb) ----------------------------

__device__ __forceinline__ void add8(float* a, uint4 u) {
    a[0] += bflo(u.x); a[1] += bfhi(u.x);
    a[2] += bflo(u.y); a[3] += bfhi(u.y);
    a[4] += bflo(u.z); a[5] += bfhi(u.z);
    a[6] += bflo(u.w); a[7] += bfhi(u.w);
}

__device__ __forceinline__ void agg_pair(const u16* __restrict__ hw,
                                         const int* __restrict__ rp8,
                                         const int* __restrict__ recs,
                                         int va, int vb, int g, int r,
                                         float* A, float* B) {
    uint4 sva = *(const uint4*)(hw + (size_t)va * DIM + r * 8);
    uint4 svb = *(const uint4*)(hw + (size_t)vb * DIM + r * 8);
    float m = (g == 0) ? 1.0f : 0.0f;  // self term counted once
    A[0] = m * bflo(sva.x); A[1] = m * bfhi(sva.x);
    A[2] = m * bflo(sva.y); A[3] = m * bfhi(sva.y);
    A[4] = m * bflo(sva.z); A[5] = m * bfhi(sva.z);
    A[6] = m * bflo(sva.w); A[7] = m * bfhi(sva.w);
    B[0] = m * bflo(svb.x); B[1] = m * bfhi(svb.x);
    B[2] = m * bflo(svb.y); B[3] = m * bfhi(svb.y);
    B[4] = m * bflo(svb.z); B[5] = m * bfhi(svb.z);
    B[6] = m * bflo(svb.w); B[7] = m * bfhi(svb.w);

    int ea = rp8[va], enda = rp8[va + 1];
    int eb = rp8[vb], endb = rp8[vb + 1];
    int2 qa = *(const int2*)(recs + ea + 2 * g);
    int2 qb = *(const int2*)(recs + eb + 2 * g);
    while (ea < enda || eb < endb) {
        int sa0 = (ea < enda) ? qa.x : NN;
        int sa1 = (ea < enda) ? qa.y : NN;
        int sb0 = (eb < endb) ? qb.x : NN;
        int sb1 = (eb < endb) ? qb.y : NN;
        uint4 ua0 = *(const uint4*)(hw + (size_t)(u32)sa0 * DIM + r * 8);
        uint4 ua1 = *(const uint4*)(hw + (size_t)(u32)sa1 * DIM + r * 8);
        uint4 ub0 = *(const uint4*)(hw + (size_t)(u32)sb0 * DIM + r * 8);
        uint4 ub1 = *(const uint4*)(hw + (size_t)(u32)sb1 * DIM + r * 8);
        ea += 8; eb += 8;
        int2 qa_n = *(const int2*)(recs + min(ea, enda - 8) + 2 * g);
        int2 qb_n = *(const int2*)(recs + min(eb, endb - 8) + 2 * g);
        add8(A, ua0); add8(A, ua1);
        add8(B, ub0); add8(B, ub1);
        qa = qa_n; qb = qb_n;
    }
}

__device__ __forceinline__ void combine_scale(float dv, const float* bias, int r,
                                              float* acc) {
#pragma unroll
    for (int j = 0; j < 8; j++) {
        acc[j] += __shfl_xor(acc[j], 16, 64);
        acc[j] += __shfl_xor(acc[j], 32, 64);
    }
    float4 b0 = ((const float4*)bias)[2 * r];
    float4 b1 = ((const float4*)bias)[2 * r + 1];
    acc[0] = fmaxf(fmaf(dv, acc[0], b0.x), 0.f);
    acc[1] = fmaxf(fmaf(dv, acc[1], b0.y), 0.f);
    acc[2] = fmaxf(fmaf(dv, acc[2], b0.z), 0.f);
    acc[3] = fmaxf(fmaf(dv, acc[3], b0.w), 0.f);
    acc[4] = fmaxf(fmaf(dv, acc[4], b1.x), 0.f);
    acc[5] = fmaxf(fmaf(dv, acc[5], b1.y), 0.f);
    acc[6] = fmaxf(fmaf(dv, acc[6], b1.z), 0.f);
    acc[7] = fmaxf(fmaf(dv, acc[7], b1.w), 0.f);
}

// fused agg (2 nodes/wave interleaved) -> LDS 16x128 tile -> @W -> hw_out
__device__ __forceinline__ void agg_gemm_block(int bb, const u16* hw_in,
                                               const int* rp8, const int* recs,
                                               const float* dinv,
                                               const float* bias, const u16* Wt,
                                               u16* hw_out, u16* sm, int tid) {
    int lane = tid & 63;
    int w = tid >> 6;
    int g = lane >> 4, r = lane & 15;
    int base = bb * 16;
#pragma unroll
    for (int p = 0; p < 2; p++) {
        int rowa = w * 4 + 2 * p;
        int va = base + rowa;
        float A[8], B[8];
        agg_pair(hw_in, rp8, recs, va, va + 1, g, r, A, B);
        combine_scale(dinv[va], bias, r, A);
        combine_scale(dinv[va + 1], bias, r, B);
        if (g == 0) {
            uint4 pk;
            pk.x = (u32)f2bf(A[0]) | ((u32)f2bf(A[1]) << 16);
            pk.y = (u32)f2bf(A[2]) | ((u32)f2bf(A[3]) << 16);
            pk.z = (u32)f2bf(A[4]) | ((u32)f2bf(A[5]) << 16);
            pk.w = (u32)f2bf(A[6]) | ((u32)f2bf(A[7]) << 16);
            *(uint4*)(sm + rowa * ROWW + r * 8) = pk;
            pk.x = (u32)f2bf(B[0]) | ((u32)f2bf(B[1]) << 16);
            pk.y = (u32)f2bf(B[2]) | ((u32)f2bf(B[3]) << 16);
            pk.z = (u32)f2bf(B[4]) | ((u32)f2bf(B[5]) << 16);
            pk.w = (u32)f2bf(B[6]) | ((u32)f2bf(B[7]) << 16);
            *(uint4*)(sm + (rowa + 1) * ROWW + r * 8) = pk;
        }
    }
    __syncthreads();
    int q = lane >> 4;
    bf16x8 Af[4];
#pragma unroll
    for (int kc = 0; kc < 4; kc++)
        Af[kc] = *(const bf16x8*)(sm + r * ROWW + kc * 32 + q * 8);
    float dv[4];
#pragma unroll
    for (int i = 0; i < 4; i++) dv[i] = dinv[base + q * 4 + i];
#pragma unroll
    for (int t = 0; t < 2; t++) {
        int nt = w * 2 + t;
        f32x4 acc = {0.f, 0.f, 0.f, 0.f};
#pragma unroll
        for (int kc = 0; kc < 4; kc++) {
            bf16x8 Bf = *(const bf16x8*)(Wt + ((nt * 16 + r) << 7) + kc * 32 + q * 8);
            acc = __builtin_amdgcn_mfma_f32_16x16x32_bf16(Af[kc], Bf, acc, 0, 0, 0);
        }
#pragma unroll
        for (int i = 0; i < 4; i++)
            hw_out[(size_t)(base + q * 4 + i) * DIM + nt * 16 + r] = f2bf(dv[i] * acc[i]);
    }
}

__device__ __forceinline__ void agg_out_block(int bb, const u16* hw_in,
                                              const int* rp8, const int* recs,
                                              const float* dinv,
                                              const float* bias, float* out,
                                              int tid) {
    int lane = tid & 63;
    int w = tid >> 6;
    int g = lane >> 4, r = lane & 15;
    int va = bb * 8 + w * 2;  // bb < 6250
    float A[8], B[8];
    agg_pair(hw_in, rp8, recs, va, va + 1, g, r, A, B);
    combine_scale(dinv[va], bias, r, A);
    combine_scale(dinv[va + 1], bias, r, B);
    if (g == 0) {
        float4* p = (float4*)(out + (size_t)va * DIM + r * 8);
        p[0] = make_float4(A[0], A[1], A[2], A[3]);
        p[1] = make_float4(A[4], A[5], A[6], A[7]);
        p = (float4*)(out + (size_t)(va + 1) * DIM + r * 8);
        p[0] = make_float4(B[0], B[1], B[2], B[3]);
        p[1] = make_float4(B[4], B[5], B[6], B[7]);
    }
}

// gemm_f32 tile (per wave), B-frags loaded per-nt to keep VGPR low
__device__ __forceinline__ void gemm_f32_tile(int tile, const float* x,
                                              const u16* Wt, const float* dinv,
                                              u16* hwb, int lane) {
    int r = lane & 15, q = lane >> 4;
    long rowbase = (long)tile * 16;
    bf16x8 Af[4];
#pragma unroll
    for (int kc = 0; kc < 4; kc++) {
        const float4* p = (const float4*)(x + (rowbase + r) * 128 + kc * 32 + q * 8);
        float4 t0 = p[0], t1 = p[1];
        bf16x8 a;
        a[0] = (short)f2bf(t0.x); a[1] = (short)f2bf(t0.y);
        a[2] = (short)f2bf(t0.z); a[3] = (short)f2bf(t0.w);
        a[4] = (short)f2bf(t1.x); a[5] = (short)f2bf(t1.y);
        a[6] = (short)f2bf(t1.z); a[7] = (short)f2bf(t1.w);
        Af[kc] = a;
    }
    float dv[4];
#pragma unroll
    for (int i = 0; i < 4; i++) dv[i] = dinv[rowbase + q * 4 + i];
#pragma unroll
    for (int nt = 0; nt < 8; nt++) {
        f32x4 acc = {0.f, 0.f, 0.f, 0.f};
#pragma unroll
        for (int kc = 0; kc < 4; kc++) {
            bf16x8 Bf = *(const bf16x8*)(Wt + ((nt * 16 + r) << 7) + kc * 32 + q * 8);
            acc = __builtin_amdgcn_mfma_f32_16x16x32_bf16(Af[kc], Bf, acc, 0, 0, 0);
        }
#pragma unroll
        for (int i = 0; i < 4; i++)
            hwb[(rowbase + q * 4 + i) * 128 + nt * 16 + r] = f2bf(dv[i] * acc[i]);
    }
}

// ---- the mega-kernel -------------------------------------------------------

__global__ __launch_bounds__(256, 4) void k_all(Params p) {
    cg::grid_group grid = cg::this_grid();
    __shared__ u16 sm[16 * ROWW];
    __shared__ int buf[256];
    __shared__ int s64s;

    int b = blockIdx.x, t = threadIdx.x, gn = gridDim.x;
    int gid = b * 256 + t;
    int stride = gn * 256;

    if (t == 0) {
        int o = 0;
#pragma unroll
        for (int j = 0; j < 16; j++) o |= p.ei[2 * j + 1];  // int64 => high 0
        s64s = (o == 0);
    }
    __syncthreads();
    int is64 = s64s;

    // phase 0: zero deg + cursor
    for (int i = gid; i < 2 * NN; i += stride) p.deg[i] = 0;
    grid.sync();

    // phase 1: count in-degrees
    for (int e = gid; e < NE; e += stride) {
        int d = is64 ? p.ei[2 * (NE + e)] : p.ei[NE + e];
        atomicAdd(&p.deg[d], 1);
    }
    grid.sync();

    // phase 2a: per-256-chunk exclusive scan of pad8(deg)
    for (int blk = b; blk < NSCAN; blk += gn) {
        int i = blk * 256 + t;
        int v = (i < NN) ? pad8(p.deg[i]) : 0;
        buf[t] = v;
        __syncthreads();
        for (int off = 1; off < 256; off <<= 1) {
            int x = (t >= off) ? buf[t - off] : 0;
            __syncthreads();
            buf[t] += x;
            __syncthreads();
        }
        if (i < NN) p.rp8[i] = buf[t] - v;
        if (t == 255) p.bsum[blk] = buf[255];
        __syncthreads();
    }
    grid.sync();

    // phase 2b: scan the block sums (block 0 only)
    if (b == 0) {
        int v = (t < NSCAN) ? p.bsum[t] : 0;
        buf[t] = v;
        __syncthreads();
        for (int off = 1; off < 256; off <<= 1) {
            int x = (t >= off) ? buf[t - off] : 0;
            __syncthreads();
            buf[t] += x;
            __syncthreads();
        }
        p.bsum[t] = buf[t] - v;  // t >= NSCAN holds grand total
    }
    grid.sync();

    // phase 2c: finalize rp8, dinv
    for (int i = gid; i < NN; i += stride) {
        p.rp8[i] += p.bsum[i >> 8];
        p.dinv[i] = rsqrtf((float)(p.deg[i] + 1));  // +1 self loop
    }
    if (gid == 0) p.rp8[NN] = p.bsum[255];
    grid.sync();

    // phase 3: fill CSR + weight cast + sentinel pads + zero sentinel rows
    {
        int* cursor = p.deg + NN;
        for (int e = gid; e < NE; e += stride) {
            int s = is64 ? p.ei[2 * e] : p.ei[e];
            int d = is64 ? p.ei[2 * (NE + e)] : p.ei[NE + e];
            int pos = p.rp8[d] + atomicAdd(&cursor[d], 1);
            p.recs[pos] = s;
        }
        for (int idx = gid; idx < 3 * 16384; idx += stride) {
            int l = idx >> 14, rem = idx & 16383;
            int n = rem >> 7, k = rem & 127;
            const float* W = (l == 0) ? p.W0 : ((l == 1) ? p.W1 : p.W2);
            p.Wt[idx] = f2bf(W[k * 128 + n]);
        }
        for (int i = gid; i < NN; i += stride) {
            int rp = p.rp8[i], d = p.deg[i], pd = pad8(d);
            for (int j = d; j < pd; j++) p.recs[rp + j] = NN;
        }
        if (gid < 64) {
            ((u32*)(p.hwA + (size_t)NN * DIM))[gid] = 0;
            ((u32*)(p.hwB + (size_t)NN * DIM))[gid] = 0;
        }
    }
    grid.sync();

    // phase 4: layer-1 GEMM  hwA = dinv * (bf16(x) @ W0)
    {
        int w = t >> 6, lane = t & 63;
        for (int tile = b * 4 + w; tile < TILES; tile += gn * 4)
            gemm_f32_tile(tile, p.x, p.Wt, p.dinv, p.hwA, lane);
    }
    grid.sync();

    // phase 5: layer-1 agg + layer-2 GEMM  hwB = dinv * (relu(agg(hwA)+b0) @ W1)
    for (int bb = b; bb < TILES; bb += gn) {
        agg_gemm_block(bb, p.hwA, p.rp8, p.recs, p.dinv, p.b0,
                       p.Wt + 16384, p.hwB, sm, t);
        __syncthreads();
    }
    grid.sync();

    // phase 6: layer-2 agg + layer-3 GEMM  hwA = dinv * (relu(agg(hwB)+b1) @ W2)
    for (int bb = b; bb < TILES; bb += gn) {
        agg_gemm_block(bb, p.hwB, p.rp8, p.recs, p.dinv, p.b1,
                       p.Wt + 32768, p.hwA, sm, t);
        __syncthreads();
    }
    grid.sync();

    // phase 7: layer-3 agg -> f32 out
    for (int bb = b; bb < 6250; bb += gn)
        agg_out_block(bb, p.hwA, p.rp8, p.recs, p.dinv, p.b2, p.out, t);
}

// ---- launch ----------------------------------------------------------------

extern "C" void kernel_launch(void* const* d_in, const int* in_sizes, int n_in,
                              void* d_out, int out_size, void* d_ws, size_t ws_size,
                              hipStream_t stream) {
    char* ws = (char*)d_ws;
    size_t off = 0;
    auto alloc = [&](size_t bytes) -> void* {
        void* p = ws + off;
        off += (bytes + 511) & ~(size_t)511;
        return p;
    };
    Params p;
    p.ei = (const int*)d_in[1];
    p.x = (const float*)d_in[0];
    p.W0 = (const float*)d_in[2];
    p.b0 = (const float*)d_in[3];
    p.W1 = (const float*)d_in[4];
    p.b1 = (const float*)d_in[5];
    p.W2 = (const float*)d_in[6];
    p.b2 = (const float*)d_in[7];
    p.deg = (int*)alloc(2 * NN * 4);  // deg + cursor (zeroed in phase 0)
    p.recs = (int*)alloc((size_t)NEPAD * 4);
    p.dinv = (float*)alloc(NN * 4);
    p.rp8 = (int*)alloc((NN + 1) * 4);
    p.bsum = (int*)alloc(256 * 4);
    p.Wt = (u16*)alloc(3 * 128 * 128 * 2);
    p.hwA = (u16*)alloc((size_t)(NN + 1) * DIM * 2);  // +1 sentinel row
    p.hwB = (u16*)alloc((size_t)(NN + 1) * DIM * 2);
    p.out = (float*)d_out;

    int nb = 0;
    hipOccupancyMaxActiveBlocksPerMultiprocessor(&nb, (const void*)k_all, 256, 0);
    if (nb < 1) nb = 1;
    long g = (long)nb * 256;  // 256 CUs
    if (g > 1024) g = 1024;
    if (g < 256) g = 256;  // 2+ blocks/CU always fits (small LDS, <=128 VGPR)
    dim3 grid((unsigned)g), block(256);
    void* args[] = {&p};
    hipLaunchCooperativeKernel((void*)k_all, grid, block, args, 0, stream);
}

// Round 13
// 358.510 us; speedup vs baseline: 2.3468x; 2.3468x over previous
//
#include <hip/hip_runtime.h>

#define NN 50000
#define NE 600000
#define DIM 128
#define NB_N 196   // ceil(50000/256)
#define NB_E 2344  // ceil(600000/256)
#define TILES 3125 // 50000/16
#define ROWW 136   // LDS row pitch in u16 for GEMM tile (128 + 8 pad)
#define WEDGE 128  // edges staged per window (32 KB of LDS rows)
#define NEPAD (NE + 8 * NN + 64)  // rows padded to multiple of 8, min 8

typedef unsigned short u16;
typedef unsigned int u32;
typedef __attribute__((ext_vector_type(8))) short bf16x8;
typedef __attribute__((ext_vector_type(4))) float f32x4;

__device__ __forceinline__ u16 f2bf(float f) {
    u32 u = __builtin_bit_cast(u32, f);
    u32 r = (u + 0x7FFFu + ((u >> 16) & 1u)) >> 16;
    return (u16)r;
}
__device__ __forceinline__ float bflo(u32 w) { return __builtin_bit_cast(float, w << 16); }
__device__ __forceinline__ float bfhi(u32 w) { return __builtin_bit_cast(float, w & 0xffff0000u); }
__device__ __forceinline__ int pad8(int d) {
    int p = (d + 7) & ~7;
    return p < 8 ? 8 : p;
}

// async global->LDS, 16 B/lane; LDS dest = l + lane*16 (HW-fixed mapping)
__device__ __forceinline__ void dma16(const u16* g, u16* l) {
    __builtin_amdgcn_global_load_lds(
        (const __attribute__((address_space(1))) void*)g,
        (__attribute__((address_space(3))) void*)l, 16, 0, 0);
}

// ---- CSR build (identical to R8) -------------------------------------------

__global__ __launch_bounds__(256) void k_count(const int* __restrict__ ei,
                                               int* __restrict__ deg) {
    __shared__ int s64;
    if (threadIdx.x == 0) {
        int o = 0;
#pragma unroll
        for (int j = 0; j < 16; j++) o |= ei[2 * j + 1];  // int64 => high words 0
        s64 = (o == 0);
    }
    __syncthreads();
    int e = blockIdx.x * 256 + threadIdx.x;
    if (e >= NE) return;
    int d = s64 ? ei[2 * (NE + e)] : ei[NE + e];
    atomicAdd(&deg[d], 1);
}

__global__ __launch_bounds__(256) void k_scanA(const int* __restrict__ deg,
                                               int* __restrict__ rp8,
                                               int* __restrict__ bsum) {
    __shared__ int buf[256];
    int t = threadIdx.x, i = blockIdx.x * 256 + t;
    int v = (i < NN) ? pad8(deg[i]) : 0;
    buf[t] = v;
    __syncthreads();
    for (int off = 1; off < 256; off <<= 1) {
        int x = (t >= off) ? buf[t - off] : 0;
        __syncthreads();
        buf[t] += x;
        __syncthreads();
    }
    if (i < NN) rp8[i] = buf[t] - v;
    if (t == 255) bsum[blockIdx.x] = buf[255];
}

__global__ __launch_bounds__(256) void k_scanB(int* __restrict__ bsum) {
    __shared__ int buf[256];
    int t = threadIdx.x;
    int v = (t < NB_N) ? bsum[t] : 0;
    buf[t] = v;
    __syncthreads();
    for (int off = 1; off < 256; off <<= 1) {
        int x = (t >= off) ? buf[t - off] : 0;
        __syncthreads();
        buf[t] += x;
        __syncthreads();
    }
    bsum[t] = buf[t] - v;
}

__global__ __launch_bounds__(256) void k_scanC(const int* __restrict__ deg,
                                               int* __restrict__ rp8,
                                               const int* __restrict__ bsum,
                                               float* __restrict__ dinv) {
    int i = blockIdx.x * 256 + threadIdx.x;
    if (i < NN) {
        rp8[i] += bsum[i >> 8];
        dinv[i] = rsqrtf((float)(deg[i] + 1));  // +1 self loop
    }
    if (i == 0) rp8[NN] = bsum[255];
}

__global__ __launch_bounds__(256) void k_fill(const int* __restrict__ ei,
                                              const int* __restrict__ rp8,
                                              int* __restrict__ cursor,
                                              const int* __restrict__ deg,
                                              int* __restrict__ recs,
                                              const float* __restrict__ W0,
                                              const float* __restrict__ W1,
                                              const float* __restrict__ W2,
                                              u16* __restrict__ Wt,
                                              u16* __restrict__ hwA,
                                              u16* __restrict__ hwB) {
    __shared__ int s64;
    if (threadIdx.x == 0) {
        int o = 0;
#pragma unroll
        for (int j = 0; j < 16; j++) o |= ei[2 * j + 1];
        s64 = (o == 0);
    }
    __syncthreads();
    int e = blockIdx.x * 256 + threadIdx.x;
    if (e < NE) {
        int is64 = s64;
        int s = is64 ? ei[2 * e] : ei[e];
        int d = is64 ? ei[2 * (NE + e)] : ei[NE + e];
        int pos = rp8[d] + atomicAdd(&cursor[d], 1);
        recs[pos] = s;
    }
    int b = blockIdx.x;
    if (b < 192) {  // Wt[layer][n][k] = bf16(W[layer][k][n])
        int idx = b * 256 + threadIdx.x;
        int l = idx >> 14, rem = idx & 16383;
        int n = rem >> 7, k = rem & 127;
        const float* W = (l == 0) ? W0 : ((l == 1) ? W1 : W2);
        Wt[idx] = f2bf(W[k * 128 + n]);
    } else if (b < 388) {  // pad entries -> sentinel NN
        int i = (b - 192) * 256 + threadIdx.x;
        if (i < NN) {
            int rp = rp8[i], d = deg[i], p = pad8(d);
            for (int j = d; j < p; j++) recs[rp + j] = NN;
        }
    } else if (b == 388) {  // zero sentinel rows
        if (threadIdx.x < 64) {
            ((u32*)(hwA + (size_t)NN * DIM))[threadIdx.x] = 0;
            ((u32*)(hwB + (size_t)NN * DIM))[threadIdx.x] = 0;
        }
    }
}

// ---- layer-1 GEMM: hw'[v] = dinv[v] * (bf16(x) @ W0) (R8-identical) --------
__global__ __launch_bounds__(256) void k_gemm_f32(const float* __restrict__ x,
                                                  const u16* __restrict__ Wt,
                                                  const float* __restrict__ dinv,
                                                  u16* __restrict__ hwb) {
    int lane = threadIdx.x & 63;
    int tile = blockIdx.x * 4 + (threadIdx.x >> 6);
    if (tile >= TILES) return;
    int r = lane & 15, q = lane >> 4;

    bf16x8 Bf[8][4];
#pragma unroll
    for (int nt = 0; nt < 8; nt++)
#pragma unroll
        for (int kc = 0; kc < 4; kc++)
            Bf[nt][kc] = *(const bf16x8*)(Wt + ((nt * 16 + r) << 7) + kc * 32 + q * 8);

    long rowbase = (long)tile * 16;
    bf16x8 Af[4];
#pragma unroll
    for (int kc = 0; kc < 4; kc++) {
        const float4* p = (const float4*)(x + (rowbase + r) * 128 + kc * 32 + q * 8);
        float4 t0 = p[0], t1 = p[1];
        bf16x8 a;
        a[0] = (short)f2bf(t0.x); a[1] = (short)f2bf(t0.y);
        a[2] = (short)f2bf(t0.z); a[3] = (short)f2bf(t0.w);
        a[4] = (short)f2bf(t1.x); a[5] = (short)f2bf(t1.y);
        a[6] = (short)f2bf(t1.z); a[7] = (short)f2bf(t1.w);
        Af[kc] = a;
    }

    float dv[4];
#pragma unroll
    for (int i = 0; i < 4; i++) dv[i] = dinv[rowbase + q * 4 + i];

#pragma unroll
    for (int nt = 0; nt < 8; nt++) {
        f32x4 acc = {0.f, 0.f, 0.f, 0.f};
#pragma unroll
        for (int kc = 0; kc < 4; kc++)
            acc = __builtin_amdgcn_mfma_f32_16x16x32_bf16(Af[kc], Bf[nt][kc], acc, 0, 0, 0);
#pragma unroll
        for (int i = 0; i < 4; i++)
            hwb[(rowbase + q * 4 + i) * 128 + nt * 16 + r] = f2bf(dv[i] * acc[i]);
    }
}

// ---- DMA-windowed aggregation core ----------------------------------------
// Tile = 16 nodes; tile edge range [rp8[base], rp8[base+16]) is contiguous.
// Window = 128 edges: all 4 waves DMA-stage full 256-B rows into LDS
// (wave w stages edges win+w*32 .. +32; lane = edge-subslot(4) x 16B-chunk(16);
// 128 lines in flight per wave), __syncthreads drains, then wave w serially
// sums its 4 nodes' rows from LDS (u32/lane = 2 feats, conflict-free).
// acc[n][2] per lane; no cross-lane reduction needed.
__device__ __forceinline__ void agg_tile_dma(const u16* __restrict__ hw_in,
                                             const int* __restrict__ rp8,
                                             const int* __restrict__ recs,
                                             u16* smrows, int base, int w,
                                             int lane, float acc[4][2]) {
    int rb[5];
    {
        int4 nr = *(const int4*)(rp8 + base + w * 4);
        rb[0] = nr.x; rb[1] = nr.y; rb[2] = nr.z; rb[3] = nr.w;
        rb[4] = rp8[base + w * 4 + 4];
    }
    int ts = rp8[base], te = rp8[base + 16];

#pragma unroll
    for (int n = 0; n < 4; n++) {  // self terms (each lane: 2 feats of row v)
        int v = base + w * 4 + n;
        u32 sv = *(const u32*)(hw_in + (size_t)v * DIM + lane * 2);
        acc[n][0] = bflo(sv);
        acc[n][1] = bfhi(sv);
    }

    int c16 = lane >> 4;   // edge subslot within a DMA instruction
    int ch = lane & 15;    // 16-B chunk within the 256-B row
    int nw = (te - ts + WEDGE - 1) / WEDGE;
    for (int wi = 0; wi < nw; wi++) {
        int win = ts + wi * WEDGE;
#pragma unroll
        for (int k = 0; k < 8; k++) {
            int idx = win + w * 32 + k * 4 + c16;
            int rec = (idx < te) ? recs[idx] : NN;  // sentinel row = zeros
            const u16* g = hw_in + (size_t)(u32)rec * DIM + ch * 8;
            u16* l = smrows + (w * 32 + k * 4) * DIM;  // wave-uniform base
            dma16(g, l);
        }
        __syncthreads();  // drains this wave's vmcnt + block barrier
#pragma unroll
        for (int n = 0; n < 4; n++) {
            int e0 = max(rb[n], win);
            int e1 = min(rb[n + 1], win + WEDGE);
            for (int e = e0; e < e1; e++) {
                u32 u = *(const u32*)(smrows + (e - win) * DIM + lane * 2);
                acc[n][0] += bflo(u);
                acc[n][1] += bfhi(u);
            }
        }
        __syncthreads();  // reduce done before next window overwrites LDS
    }
}

// ---- fused: h = relu(dv*agg+b) -> LDS tile -> hw_out = dinv * (h @ W) ------
__global__ __launch_bounds__(256, 4) void k_aggg(const u16* __restrict__ hw_in,
                                                 const int* __restrict__ rp8,
                                                 const int* __restrict__ recs,
                                                 const float* __restrict__ dinv,
                                                 const float* __restrict__ bias,
                                                 const u16* __restrict__ Wt,
                                                 u16* __restrict__ hw_out) {
    __shared__ u16 smrows[WEDGE * DIM];  // 32 KB staged rows
    __shared__ u16 smt[16 * ROWW];       // GEMM A-tile
    int t = threadIdx.x;
    int w = t >> 6, lane = t & 63;
    int base = blockIdx.x * 16;

    float acc[4][2];
    agg_tile_dma(hw_in, rp8, recs, smrows, base, w, lane, acc);

    float2 bb = *(const float2*)(bias + lane * 2);
#pragma unroll
    for (int n = 0; n < 4; n++) {
        int v = base + w * 4 + n;
        float dv = dinv[v];
        float r0 = fmaxf(fmaf(dv, acc[n][0], bb.x), 0.f);
        float r1 = fmaxf(fmaf(dv, acc[n][1], bb.y), 0.f);
        u32 pk = (u32)f2bf(r0) | ((u32)f2bf(r1) << 16);
        *(u32*)(smt + (w * 4 + n) * ROWW + lane * 2) = pk;
    }
    __syncthreads();

    // GEMM: 16x128 LDS tile @ 128x128 W; wave w does n-tiles {2w, 2w+1}
    int r = lane & 15, q = lane >> 4;
    bf16x8 Af[4];
#pragma unroll
    for (int kc = 0; kc < 4; kc++)
        Af[kc] = *(const bf16x8*)(smt + r * ROWW + kc * 32 + q * 8);
    float dv[4];
#pragma unroll
    for (int i = 0; i < 4; i++) dv[i] = dinv[base + q * 4 + i];
#pragma unroll
    for (int tt = 0; tt < 2; tt++) {
        int nt = w * 2 + tt;
        f32x4 acc2 = {0.f, 0.f, 0.f, 0.f};
#pragma unroll
        for (int kc = 0; kc < 4; kc++) {
            bf16x8 Bf = *(const bf16x8*)(Wt + ((nt * 16 + r) << 7) + kc * 32 + q * 8);
            acc2 = __builtin_amdgcn_mfma_f32_16x16x32_bf16(Af[kc], Bf, acc2, 0, 0, 0);
        }
#pragma unroll
        for (int i = 0; i < 4; i++)
            hw_out[(size_t)(base + q * 4 + i) * DIM + nt * 16 + r] =
                f2bf(dv[i] * acc2[i]);
    }
}

// ---- final layer: relu(dv*agg+b) -> f32 out --------------------------------
__global__ __launch_bounds__(256, 4) void k_aggo(const u16* __restrict__ hw_in,
                                                 const int* __restrict__ rp8,
                                                 const int* __restrict__ recs,
                                                 const float* __restrict__ dinv,
                                                 const float* __restrict__ bias,
                                                 float* __restrict__ out) {
    __shared__ u16 smrows[WEDGE * DIM];
    int t = threadIdx.x;
    int w = t >> 6, lane = t & 63;
    int base = blockIdx.x * 16;

    float acc[4][2];
    agg_tile_dma(hw_in, rp8, recs, smrows, base, w, lane, acc);

    float2 bb = *(const float2*)(bias + lane * 2);
#pragma unroll
    for (int n = 0; n < 4; n++) {
        int v = base + w * 4 + n;
        float dv = dinv[v];
        float r0 = fmaxf(fmaf(dv, acc[n][0], bb.x), 0.f);
        float r1 = fmaxf(fmaf(dv, acc[n][1], bb.y), 0.f);
        *(float2*)(out + (size_t)v * DIM + lane * 2) = make_float2(r0, r1);
    }
}

// ---- launch ----------------------------------------------------------------

extern "C" void kernel_launch(void* const* d_in, const int* in_sizes, int n_in,
                              void* d_out, int out_size, void* d_ws, size_t ws_size,
                              hipStream_t stream) {
    const float* x = (const float*)d_in[0];
    const int* ei = (const int*)d_in[1];
    const float* W0 = (const float*)d_in[2];
    const float* b0 = (const float*)d_in[3];
    const float* W1 = (const float*)d_in[4];
    const float* b1 = (const float*)d_in[5];
    const float* W2 = (const float*)d_in[6];
    const float* b2 = (const float*)d_in[7];

    char* ws = (char*)d_ws;
    size_t off = 0;
    auto alloc = [&](size_t bytes) -> void* {
        void* p = ws + off;
        off += (bytes + 511) & ~(size_t)511;
        return p;
    };
    int* deg = (int*)alloc(NN * 4);      // zeroed
    int* cursor = (int*)alloc(NN * 4);   // zeroed
    size_t zbytes = off;
    int* recs = (int*)alloc((size_t)NEPAD * 4);
    float* dinv = (float*)alloc(NN * 4);
    int* rp8 = (int*)alloc((NN + 1) * 4);
    int* bsum = (int*)alloc(256 * 4);
    u16* Wt = (u16*)alloc(3 * 128 * 128 * 2);
    u16* hwA = (u16*)alloc((size_t)(NN + 1) * DIM * 2);  // +1 sentinel row
    u16* hwB = (u16*)alloc((size_t)(NN + 1) * DIM * 2);

    hipMemsetAsync(ws, 0, zbytes, stream);
    k_count<<<NB_E, 256, 0, stream>>>(ei, deg);
    k_scanA<<<NB_N, 256, 0, stream>>>(deg, rp8, bsum);
    k_scanB<<<1, 256, 0, stream>>>(bsum);
    k_scanC<<<NB_N, 256, 0, stream>>>(deg, rp8, bsum, dinv);
    k_fill<<<NB_E, 256, 0, stream>>>(ei, rp8, cursor, deg, recs,
                                     W0, W1, W2, Wt, hwA, hwB);
    k_gemm_f32<<<(TILES + 3) / 4, 256, 0, stream>>>(x, Wt, dinv, hwA);
    k_aggg<<<TILES, 256, 0, stream>>>(hwA, rp8, recs, dinv, b0,
                                      Wt + 16384, hwB);
    k_aggg<<<TILES, 256, 0, stream>>>(hwB, rp8, recs, dinv, b1,
                                      Wt + 32768, hwA);
    k_aggo<<<TILES, 256, 0, stream>>>(hwA, rp8, recs, dinv, b2,
                                      (float*)d_out);
}